// Round 9
// baseline (482.195 us; speedup 1.0000x reference)
//
#include <hip/hip_runtime.h>
#include <hip/hip_bf16.h>
#include <hip/hip_fp8.h>
#include <math.h>

#define Ddim 1024
#define Mrows 4096
#define Ncols 8192
#define BM 128
#define BN 128
#define BKB 64                         // K-bytes per tile (fp8: 64 elems)
#define NCS 64                         // 64 col-split blocks of 128 cols
#define CS 128                         // lse partials per row (64 cols each)
#define RT (Mrows / BM)                // 32
#define KITERS (Ddim / BKB)            // 16
#define SCALE 20.0f                    // 1/TEMPERATURE
#define ARR_ELEMS (Mrows * Ddim)       // 4194304 per input array

typedef float f32x16 __attribute__((ext_vector_type(16)));
typedef int i32x4 __attribute__((ext_vector_type(4)));
typedef int i32x8 __attribute__((ext_vector_type(8)));

// global->LDS DMA, 16B per lane, lds dest = wave-uniform base + lane*16
#define LOAD16_TO_LDS(g, l)                                                  \
  __builtin_amdgcn_global_load_lds(                                          \
      (const __attribute__((address_space(1))) void*)(g),                    \
      (__attribute__((address_space(3))) void*)(l), 16, 0, 0)

// ---------------------------------------------------------------------------
// Kernel 0: f32 -> fp8 e4m3 (OCP) conversion pre-pass
// ---------------------------------------------------------------------------
__global__ __launch_bounds__(256) void cvt_kernel(
    const float* __restrict__ o, const float* __restrict__ pos,
    const float* __restrict__ neg, unsigned char* __restrict__ ob,
    unsigned char* __restrict__ pb, unsigned char* __restrict__ nb)
{
  const int idx = blockIdx.x * 256 + threadIdx.x;   // 0 .. 3*ARR/8-1
  const int seg = idx >> 19;                        // ARR_ELEMS/8 = 2^19
  const int off = idx & ((1 << 19) - 1);
  const float* src = (seg == 0) ? o : (seg == 1) ? pos : neg;
  unsigned char* dst = (seg == 0) ? ob : (seg == 1) ? pb : nb;
  const float4 v0 = *(const float4*)(src + (size_t)off * 8);
  const float4 v1 = *(const float4*)(src + (size_t)off * 8 + 4);
  union { unsigned char b[8]; uint2 u; } pk;
  pk.b[0] = __hip_fp8_e4m3(v0.x).__x;
  pk.b[1] = __hip_fp8_e4m3(v0.y).__x;
  pk.b[2] = __hip_fp8_e4m3(v0.z).__x;
  pk.b[3] = __hip_fp8_e4m3(v0.w).__x;
  pk.b[4] = __hip_fp8_e4m3(v1.x).__x;
  pk.b[5] = __hip_fp8_e4m3(v1.y).__x;
  pk.b[6] = __hip_fp8_e4m3(v1.z).__x;
  pk.b[7] = __hip_fp8_e4m3(v1.w).__x;
  *(uint2*)(dst + (size_t)off * 8) = pk.u;
}

// ---------------------------------------------------------------------------
// Kernel 1: fp8 MX-GEMM (o · emb^T) + partial LSE + diagonal extraction.
// 128x128 block, 2x2 waves of 64x64 tiles via mfma_scale_f32_32x32x64_f8f6f4
// (scales fixed at 1.0 = 0x7F E8M0; fmt 0 = e4m3). BK = 64 fp8 = 64 B rows:
// identical staging geometry to the bf16 version (DMA + XOR chunk swizzle,
// 0 conflicts measured R4-R8). KITERS = 16 (half the barriers of bf16).
// A/B frag: lane holds rows (lane&31), k = (lane>>5)*32 + j  (two b128).
// C/D: col = lane&31, row = (reg&3) + 8*(reg>>2) + 4*(lane>>5)  [m74/m101].
// R5 lesson: acc[][] indexed only with compile-time constants.
// ---------------------------------------------------------------------------
__global__ __launch_bounds__(256, 4) void gemm_lse_kernel(
    const unsigned char* __restrict__ ob, const unsigned char* __restrict__ pb,
    const unsigned char* __restrict__ nb, float* __restrict__ pm,
    float* __restrict__ pl, float* __restrict__ blocks_raw)
{
  __shared__ unsigned char As[2][BM * BKB];   // 2 x 8 KB
  __shared__ unsigned char Bs[2][BN * BKB];   // 2 x 8 KB

  const int bid = blockIdx.x;
  const int rt = bid >> 6;        // 0..31
  const int cs = bid & 63;        // 0..63
  const int row0 = rt * BM;
  const unsigned char* Eb = (cs < 32)
      ? (pb + (size_t)cs * BN * Ddim)
      : (nb + (size_t)(cs - 32) * BN * Ddim);

  const int t = threadIdx.x;
  const int wave = t >> 6;
  const int wr = wave & 1;        // row half (64 rows)
  const int wc = wave >> 1;       // col half (64 cols)
  const int lane = t & 63;
  const int h = lane >> 5;        // lane half (K half for frags)
  const int r31 = lane & 31;
  const int rstg = wave * 32 + (lane >> 2);   // staging source row (+16*cl)
  const int cstg = lane & 3;                  // staging 16B-chunk id

  // fragment read chunk ids (XOR-deswizzled), uniform over fm/fn since
  // row offsets are multiples of 32: g depends on r31 only
  const int gfrag = (r31 >> 1) & 3;
  const int c0 = (2 * h) ^ gfrag;
  const int c1 = (2 * h + 1) ^ gfrag;

  f32x16 acc[2][2];
#pragma unroll
  for (int a = 0; a < 2; ++a)
#pragma unroll
    for (int b = 0; b < 2; ++b)
#pragma unroll
      for (int e = 0; e < 16; ++e) acc[a][b][e] = 0.f;

  // prologue: stage tile 0 into buffer 0 (each wave: 32 rows A + 32 rows B)
#pragma unroll
  for (int cl = 0; cl < 2; ++cl) {
    const int r = rstg + cl * 16;
    const int gc = cstg ^ ((r >> 1) & 3);
    LOAD16_TO_LDS(ob + (size_t)(row0 + r) * Ddim + gc * 16,
                  &As[0][(wave * 32 + cl * 16) * BKB]);
    LOAD16_TO_LDS(Eb + (size_t)r * Ddim + gc * 16,
                  &Bs[0][(wave * 32 + cl * 16) * BKB]);
  }

  int p = 0;
  for (int kc = 0; kc < KITERS; ++kc) {
    __syncthreads();   // drains DMA for buf p; protects buf p^1 reuse
    if (kc + 1 < KITERS) {
      const int k0 = (kc + 1) * BKB;
#pragma unroll
      for (int cl = 0; cl < 2; ++cl) {
        const int r = rstg + cl * 16;
        const int gc = cstg ^ ((r >> 1) & 3);
        LOAD16_TO_LDS(ob + (size_t)(row0 + r) * Ddim + k0 + gc * 16,
                      &As[p ^ 1][(wave * 32 + cl * 16) * BKB]);
        LOAD16_TO_LDS(Eb + (size_t)r * Ddim + k0 + gc * 16,
                      &Bs[p ^ 1][(wave * 32 + cl * 16) * BKB]);
      }
    }

    i32x8 af[2], bf[2];
#pragma unroll
    for (int fm = 0; fm < 2; ++fm) {
      const unsigned char* base = &As[p][(wr * 64 + fm * 32 + r31) * BKB];
      const i32x4 lo = *(const i32x4*)(base + c0 * 16);
      const i32x4 hi = *(const i32x4*)(base + c1 * 16);
      af[fm][0] = lo[0]; af[fm][1] = lo[1]; af[fm][2] = lo[2]; af[fm][3] = lo[3];
      af[fm][4] = hi[0]; af[fm][5] = hi[1]; af[fm][6] = hi[2]; af[fm][7] = hi[3];
    }
#pragma unroll
    for (int fn = 0; fn < 2; ++fn) {
      const unsigned char* base = &Bs[p][(wc * 64 + fn * 32 + r31) * BKB];
      const i32x4 lo = *(const i32x4*)(base + c0 * 16);
      const i32x4 hi = *(const i32x4*)(base + c1 * 16);
      bf[fn][0] = lo[0]; bf[fn][1] = lo[1]; bf[fn][2] = lo[2]; bf[fn][3] = lo[3];
      bf[fn][4] = hi[0]; bf[fn][5] = hi[1]; bf[fn][6] = hi[2]; bf[fn][7] = hi[3];
    }
#pragma unroll
    for (int fn = 0; fn < 2; ++fn)
#pragma unroll
      for (int fm = 0; fm < 2; ++fm)
        acc[fm][fn] = __builtin_amdgcn_mfma_scale_f32_32x32x64_f8f6f4(
            af[fm], bf[fn], acc[fm][fn], 0, 0,
            0, 0x7F7F7F7F, 0, 0x7F7F7F7F);   // fmt e4m3/e4m3, scales = 1.0
    p ^= 1;
  }

  // epilogue A: per-row (m, l) over this wave's 64 cols.
  const int csp = cs * 2 + wc;     // partial-lse column index (0..127)
#pragma unroll
  for (int fm = 0; fm < 2; ++fm) {
#pragma unroll
    for (int reg = 0; reg < 16; ++reg) {
      const float s0 = acc[fm][0][reg] * SCALE;
      const float s1 = acc[fm][1][reg] * SCALE;
      float m = fmaxf(s0, s1);
#pragma unroll
      for (int off = 1; off <= 16; off <<= 1)
        m = fmaxf(m, __shfl_xor(m, off, 64));   // reduce within 32-lane half
      float l = __expf(s0 - m) + __expf(s1 - m);
#pragma unroll
      for (int off = 1; off <= 16; off <<= 1)
        l += __shfl_xor(l, off, 64);
      if (r31 == 0) {
        const int rg = row0 + wr * 64 + fm * 32 +
                       (reg & 3) + 8 * (reg >> 2) + 4 * h;
        pm[(size_t)rg * CS + csp] = m;
        pl[(size_t)rg * CS + csp] = l;
      }
    }
  }

  // epilogue B: diagonal 16x16 sub-blocks (block cs==rt, waves wr==wc,
  // acc[fm][fm]); guard r16==c16 is a runtime lane test, acc idx compile-time.
  if (cs == rt && wr == wc) {
#pragma unroll
    for (int fm = 0; fm < 2; ++fm) {
#pragma unroll
      for (int reg = 0; reg < 16; ++reg) {
        const int r16 = reg >> 3;                 // row_local >= 16
        if (((lane >> 4) & 1) == r16) {
          const int bb = rt * 8 + wr * 4 + fm * 2 + r16;
          const int row_in = (reg & 3) + 8 * ((reg >> 2) & 1) + 4 * h;
          blocks_raw[bb * 256 + row_in * 16 + (lane & 15)] =
              acc[fm][fm][reg] * SCALE;
        }
      }
    }
  }
}

// ---------------------------------------------------------------------------
// Kernel 2: fused lse-combine + lane-parallel JV LAP + atomic loss.
// (R7 v2 — best measured variant.) Single wave per block, no barriers;
// u[] in row-lane registers; C in LDS.
// ---------------------------------------------------------------------------
__global__ __launch_bounds__(64) void hungarian_kernel(
    const float* __restrict__ blocks_raw, const float* __restrict__ pm,
    const float* __restrict__ pl, float* __restrict__ out)
{
  const int b = blockIdx.x;
  const int L = threadIdx.x;
  __shared__ float C[16][16];
  __shared__ float lse_s[16];

  for (int e = L; e < 256; e += 64)
    C[e >> 4][e & 15] = blocks_raw[b * 256 + e];

  {
    const int r = L & 15, g = L >> 4;
    const size_t base = (size_t)(b * 16 + r) * CS + g * 32;
    float m = -INFINITY, l = 0.f;
#pragma unroll
    for (int k = 0; k < 32; ++k) {
      const float m2 = pm[base + k];
      const float l2 = pl[base + k];
      const float M = fmaxf(m, m2);
      l = l * __expf(m - M) + l2 * __expf(m2 - M);
      m = M;
    }
#pragma unroll
    for (int off = 16; off <= 32; off <<= 1) {
      const float m2 = __shfl_xor(m, off, 64);
      const float l2 = __shfl_xor(l, off, 64);
      const float M = fmaxf(m, m2);
      l = l * __expf(m - M) + l2 * __expf(m2 - M);
      m = M;
    }
    if (g == 0) lse_s[r] = m + logf(l);
  }

  const float INF = 3.0e38f;
  float vj = 0.f, u_reg = 0.f;
  int pj = 0;
  float minv = INF;
  int wayj = 0;
  bool usedj = false, on_tree = false;

  for (int i = 1; i <= 16; ++i) {
    if (L == 0) pj = i;
    minv = INF; wayj = 0; usedj = false; on_tree = false;
    int j0 = 0;
    while (true) {
      usedj = usedj || (L == j0);
      const int i0 = __shfl(pj, j0, 64);
      if (L == i0) on_tree = true;
      const float ui0 = __shfl(u_reg, i0, 64);
      if (L >= 1 && L <= 16 && !usedj) {
        const float cur = -C[i0 - 1][L - 1] - ui0 - vj;
        if (cur < minv) { minv = cur; wayj = j0; }
      }
      float cand = (L >= 1 && L <= 16 && !usedj) ? minv : INF;
      int idx = L;
#pragma unroll
      for (int off = 16; off > 0; off >>= 1) {
        const float ov = __shfl_xor(cand, off, 32);
        const int oi = __shfl_xor(idx, off, 32);
        if (ov < cand || (ov == cand && oi < idx)) { cand = ov; idx = oi; }
      }
      const float delta = cand;                  // valid in lanes 0..31
      const int j1 = __builtin_amdgcn_readfirstlane(idx);
      if (L >= 1 && L <= 16) {
        if (usedj) vj -= delta; else minv -= delta;
        if (on_tree) u_reg += delta;
      }
      j0 = j1;
      const int pj0 = __shfl(pj, j0, 64);
      if (pj0 == 0) break;
    }
    while (j0 != 0) {
      const int j1a = __shfl(wayj, j0, 64);
      const int pjn = __shfl(pj, j1a, 64);
      if (L == j0) pj = pjn;
      j0 = j1a;
    }
  }

  float loss = 0.f;
  if (L >= 1 && L <= 16) loss = lse_s[pj - 1] - C[pj - 1][L - 1];
#pragma unroll
  for (int off = 32; off > 0; off >>= 1) loss += __shfl_down(loss, off, 64);
  if (L == 0) atomicAdd(out, loss * (1.0f / 4096.0f));
}

extern "C" void kernel_launch(void* const* d_in, const int* in_sizes, int n_in,
                              void* d_out, int out_size, void* d_ws, size_t ws_size,
                              hipStream_t stream) {
  const float* o   = (const float*)d_in[0];  // (256,16,1024) f32
  const float* pos = (const float*)d_in[1];
  const float* neg = (const float*)d_in[2];
  float* out = (float*)d_out;

  float* ws = (float*)d_ws;
  float* pm         = ws;                       // 4096*128 = 2 MB
  float* pl         = pm + (size_t)4096 * CS;   // 4096*128 = 2 MB
  float* blocks_raw = pl + (size_t)4096 * CS;   // 256*256
  unsigned char* ob = (unsigned char*)(blocks_raw + 65536);  // 3 x 4 MB fp8
  unsigned char* pb = ob + (size_t)ARR_ELEMS;
  unsigned char* nb = pb + (size_t)ARR_ELEMS;

  hipMemsetAsync(out, 0, sizeof(float), stream);
  cvt_kernel<<<3 * ARR_ELEMS / 8 / 256, 256, 0, stream>>>(o, pos, neg, ob, pb, nb);
  gemm_lse_kernel<<<RT * NCS, 256, 0, stream>>>(ob, pb, nb, pm, pl, blocks_raw);
  hungarian_kernel<<<256, 64, 0, stream>>>(blocks_raw, pm, pl, out);
}

// Round 10
// 387.086 us; speedup vs baseline: 1.2457x; 1.2457x over previous
//
#include <hip/hip_runtime.h>
#include <hip/hip_bf16.h>
#include <hip/hip_fp8.h>
#include <math.h>

#define Ddim 1024
#define Mrows 4096
#define Ncols 8192
#define BM 128
#define BN 128
#define BKB 64                         // K-bytes per tile (fp8: 64 elems)
#define NCS 64                         // 64 col-split blocks of 128 cols
#define CS 128                         // lse partials per row (64 cols each)
#define RT (Mrows / BM)                // 32
#define KITERS (Ddim / BKB)            // 16
#define SCALE 20.0f                    // 1/TEMPERATURE
#define ARR_ELEMS (Mrows * Ddim)       // 4194304 per input array

typedef float f32x16 __attribute__((ext_vector_type(16)));
typedef int i32x4 __attribute__((ext_vector_type(4)));
typedef int i32x8 __attribute__((ext_vector_type(8)));

// global->LDS DMA, 16B per lane, lds dest = wave-uniform base + lane*16
#define LOAD16_TO_LDS(g, l)                                                  \
  __builtin_amdgcn_global_load_lds(                                          \
      (const __attribute__((address_space(1))) void*)(g),                    \
      (__attribute__((address_space(3))) void*)(l), 16, 0, 0)

// ---------------------------------------------------------------------------
// Kernel 0: f32 -> fp8 e4m3 (OCP) conversion pre-pass
// ---------------------------------------------------------------------------
__global__ __launch_bounds__(256) void cvt_kernel(
    const float* __restrict__ o, const float* __restrict__ pos,
    const float* __restrict__ neg, unsigned char* __restrict__ ob,
    unsigned char* __restrict__ pb, unsigned char* __restrict__ nb)
{
  const int idx = blockIdx.x * 256 + threadIdx.x;   // 0 .. 3*ARR/8-1
  const int seg = idx >> 19;                        // ARR_ELEMS/8 = 2^19
  const int off = idx & ((1 << 19) - 1);
  const float* src = (seg == 0) ? o : (seg == 1) ? pos : neg;
  unsigned char* dst = (seg == 0) ? ob : (seg == 1) ? pb : nb;
  const float4 v0 = *(const float4*)(src + (size_t)off * 8);
  const float4 v1 = *(const float4*)(src + (size_t)off * 8 + 4);
  union { unsigned char b[8]; uint2 u; } pk;
  pk.b[0] = __hip_fp8_e4m3(v0.x).__x;
  pk.b[1] = __hip_fp8_e4m3(v0.y).__x;
  pk.b[2] = __hip_fp8_e4m3(v0.z).__x;
  pk.b[3] = __hip_fp8_e4m3(v0.w).__x;
  pk.b[4] = __hip_fp8_e4m3(v1.x).__x;
  pk.b[5] = __hip_fp8_e4m3(v1.y).__x;
  pk.b[6] = __hip_fp8_e4m3(v1.z).__x;
  pk.b[7] = __hip_fp8_e4m3(v1.w).__x;
  *(uint2*)(dst + (size_t)off * 8) = pk.u;
}

// ---------------------------------------------------------------------------
// Kernel 1: fp8 MX-GEMM (o · emb^T) + partial LSE + diagonal extraction.
// 128x128 block, 2x2 waves of 64x64 via mfma_scale_f32_32x32x64_f8f6f4
// (scales = 1.0 / 0x7F E8M0, fmt e4m3). Q-PLANE LDS layout: k-chunk (q,h)
// of row r at q*4096 + r*32 + h*16 -> each fragment b128 read tiles a
// contiguous 1 KB (conflict-free pattern per R7/m98) and reproduces the
// K-mapping verified in R9 (af[0..3]=k[32h..+16) from q0, af[4..7] from q1).
// Register diet vs R9 (which spilled 692 MB): bf in-loop, shufflevector
// assembly, launch_bounds(256,3). acc[][] compile-time indices only (R5).
// ---------------------------------------------------------------------------
__global__ __launch_bounds__(256, 3) void gemm_lse_kernel(
    const unsigned char* __restrict__ ob, const unsigned char* __restrict__ pb,
    const unsigned char* __restrict__ nb, float* __restrict__ pm,
    float* __restrict__ pl, float* __restrict__ blocks_raw)
{
  __shared__ unsigned char As[2][BM * BKB];   // 2 x 8 KB (2 q-planes of 4 KB)
  __shared__ unsigned char Bs[2][BN * BKB];   // 2 x 8 KB

  const int bid = blockIdx.x;
  const int rt = bid >> 6;        // 0..31
  const int cs = bid & 63;        // 0..63
  const int row0 = rt * BM;
  const unsigned char* Eb = (cs < 32)
      ? (pb + (size_t)cs * BN * Ddim)
      : (nb + (size_t)(cs - 32) * BN * Ddim);

  const int t = threadIdx.x;
  const int wave = t >> 6;
  const int wr = wave & 1;        // row half (64 rows)
  const int wc = wave >> 1;       // col half (64 cols)
  const int lane = t & 63;
  const int h = lane >> 5;        // K-half for fragments
  const int r31 = lane & 31;

  // staging: lane l covers global row (w*32 + (l>>1)), byte offset (l&1)*32
  const size_t srcArow = (size_t)(row0 + wave * 32 + (lane >> 1)) * Ddim + (lane & 1) * 32;
  const size_t srcBrow = (size_t)(wave * 32 + (lane >> 1)) * Ddim + (lane & 1) * 32;
  const int dstOff = wave * 1024;            // + q*4096, lane*16 implicit

  f32x16 acc[2][2];
#pragma unroll
  for (int a = 0; a < 2; ++a)
#pragma unroll
    for (int b = 0; b < 2; ++b)
#pragma unroll
      for (int e = 0; e < 16; ++e) acc[a][b][e] = 0.f;

  // prologue: stage tile 0 into buffer 0 (per wave: 2 q-planes x (A + B))
#pragma unroll
  for (int q = 0; q < 2; ++q) {
    LOAD16_TO_LDS(ob + srcArow + q * 16, &As[0][q * 4096 + dstOff]);
    LOAD16_TO_LDS(Eb + srcBrow + q * 16, &Bs[0][q * 4096 + dstOff]);
  }

  const int sc1 = 0x7F7F7F7F;   // four E8M0 scales = 1.0

  int p = 0;
  for (int kc = 0; kc < KITERS; ++kc) {
    __syncthreads();   // drains DMA for buf p; protects buf p^1 reuse
    if (kc + 1 < KITERS) {
      const int k0 = (kc + 1) * BKB;
#pragma unroll
      for (int q = 0; q < 2; ++q) {
        LOAD16_TO_LDS(ob + srcArow + k0 + q * 16, &As[p ^ 1][q * 4096 + dstOff]);
        LOAD16_TO_LDS(Eb + srcBrow + k0 + q * 16, &Bs[p ^ 1][q * 4096 + dstOff]);
      }
    }

    i32x8 af[2];
#pragma unroll
    for (int fm = 0; fm < 2; ++fm) {
      const int ra = (wr * 64 + fm * 32 + r31) * 32 + h * 16;
      const i32x4 lo = *(const i32x4*)&As[p][ra];          // q0: k[32h, +16)
      const i32x4 hi = *(const i32x4*)&As[p][4096 + ra];   // q1: k[32h+16, +16)
      af[fm] = __builtin_shufflevector(lo, hi, 0, 1, 2, 3, 4, 5, 6, 7);
    }
#pragma unroll
    for (int fn = 0; fn < 2; ++fn) {
      const int rb = (wc * 64 + fn * 32 + r31) * 32 + h * 16;
      const i32x4 lo = *(const i32x4*)&Bs[p][rb];
      const i32x4 hi = *(const i32x4*)&Bs[p][4096 + rb];
      const i32x8 bf = __builtin_shufflevector(lo, hi, 0, 1, 2, 3, 4, 5, 6, 7);
#pragma unroll
      for (int fm = 0; fm < 2; ++fm)
        acc[fm][fn] = __builtin_amdgcn_mfma_scale_f32_32x32x64_f8f6f4(
            af[fm], bf, acc[fm][fn], 0, 0, 0, sc1, 0, sc1);
    }
    p ^= 1;
  }

  // epilogue A: per-row (m, l) over this wave's 64 cols. (verified R9)
  const int csp = cs * 2 + wc;     // partial-lse column index (0..127)
#pragma unroll
  for (int fm = 0; fm < 2; ++fm) {
#pragma unroll
    for (int reg = 0; reg < 16; ++reg) {
      const float s0 = acc[fm][0][reg] * SCALE;
      const float s1 = acc[fm][1][reg] * SCALE;
      float m = fmaxf(s0, s1);
#pragma unroll
      for (int off = 1; off <= 16; off <<= 1)
        m = fmaxf(m, __shfl_xor(m, off, 64));   // reduce within 32-lane half
      float l = __expf(s0 - m) + __expf(s1 - m);
#pragma unroll
      for (int off = 1; off <= 16; off <<= 1)
        l += __shfl_xor(l, off, 64);
      if (r31 == 0) {
        const int rg = row0 + wr * 64 + fm * 32 +
                       (reg & 3) + 8 * (reg >> 2) + 4 * h;
        pm[(size_t)rg * CS + csp] = m;
        pl[(size_t)rg * CS + csp] = l;
      }
    }
  }

  // epilogue B: diagonal 16x16 sub-blocks (verified R9; acc idx compile-time)
  if (cs == rt && wr == wc) {
#pragma unroll
    for (int fm = 0; fm < 2; ++fm) {
#pragma unroll
      for (int reg = 0; reg < 16; ++reg) {
        const int r16 = reg >> 3;                 // row_local >= 16
        if (((lane >> 4) & 1) == r16) {
          const int bb = rt * 8 + wr * 4 + fm * 2 + r16;
          const int row_in = (reg & 3) + 8 * ((reg >> 2) & 1) + 4 * h;
          blocks_raw[bb * 256 + row_in * 16 + (lane & 15)] =
              acc[fm][fm][reg] * SCALE;
        }
      }
    }
  }
}

// ---------------------------------------------------------------------------
// Kernel 2: fused lse-combine + lane-parallel JV LAP + atomic loss.
// (R7 v2 — best measured variant.)
// ---------------------------------------------------------------------------
__global__ __launch_bounds__(64) void hungarian_kernel(
    const float* __restrict__ blocks_raw, const float* __restrict__ pm,
    const float* __restrict__ pl, float* __restrict__ out)
{
  const int b = blockIdx.x;
  const int L = threadIdx.x;
  __shared__ float C[16][16];
  __shared__ float lse_s[16];

  for (int e = L; e < 256; e += 64)
    C[e >> 4][e & 15] = blocks_raw[b * 256 + e];

  {
    const int r = L & 15, g = L >> 4;
    const size_t base = (size_t)(b * 16 + r) * CS + g * 32;
    float m = -INFINITY, l = 0.f;
#pragma unroll
    for (int k = 0; k < 32; ++k) {
      const float m2 = pm[base + k];
      const float l2 = pl[base + k];
      const float M = fmaxf(m, m2);
      l = l * __expf(m - M) + l2 * __expf(m2 - M);
      m = M;
    }
#pragma unroll
    for (int off = 16; off <= 32; off <<= 1) {
      const float m2 = __shfl_xor(m, off, 64);
      const float l2 = __shfl_xor(l, off, 64);
      const float M = fmaxf(m, m2);
      l = l * __expf(m - M) + l2 * __expf(m2 - M);
      m = M;
    }
    if (g == 0) lse_s[r] = m + logf(l);
  }

  const float INF = 3.0e38f;
  float vj = 0.f, u_reg = 0.f;
  int pj = 0;
  float minv = INF;
  int wayj = 0;
  bool usedj = false, on_tree = false;

  for (int i = 1; i <= 16; ++i) {
    if (L == 0) pj = i;
    minv = INF; wayj = 0; usedj = false; on_tree = false;
    int j0 = 0;
    while (true) {
      usedj = usedj || (L == j0);
      const int i0 = __shfl(pj, j0, 64);
      if (L == i0) on_tree = true;
      const float ui0 = __shfl(u_reg, i0, 64);
      if (L >= 1 && L <= 16 && !usedj) {
        const float cur = -C[i0 - 1][L - 1] - ui0 - vj;
        if (cur < minv) { minv = cur; wayj = j0; }
      }
      float cand = (L >= 1 && L <= 16 && !usedj) ? minv : INF;
      int idx = L;
#pragma unroll
      for (int off = 16; off > 0; off >>= 1) {
        const float ov = __shfl_xor(cand, off, 32);
        const int oi = __shfl_xor(idx, off, 32);
        if (ov < cand || (ov == cand && oi < idx)) { cand = ov; idx = oi; }
      }
      const float delta = cand;                  // valid in lanes 0..31
      const int j1 = __builtin_amdgcn_readfirstlane(idx);
      if (L >= 1 && L <= 16) {
        if (usedj) vj -= delta; else minv -= delta;
        if (on_tree) u_reg += delta;
      }
      j0 = j1;
      const int pj0 = __shfl(pj, j0, 64);
      if (pj0 == 0) break;
    }
    while (j0 != 0) {
      const int j1a = __shfl(wayj, j0, 64);
      const int pjn = __shfl(pj, j1a, 64);
      if (L == j0) pj = pjn;
      j0 = j1a;
    }
  }

  float loss = 0.f;
  if (L >= 1 && L <= 16) loss = lse_s[pj - 1] - C[pj - 1][L - 1];
#pragma unroll
  for (int off = 32; off > 0; off >>= 1) loss += __shfl_down(loss, off, 64);
  if (L == 0) atomicAdd(out, loss * (1.0f / 4096.0f));
}

extern "C" void kernel_launch(void* const* d_in, const int* in_sizes, int n_in,
                              void* d_out, int out_size, void* d_ws, size_t ws_size,
                              hipStream_t stream) {
  const float* o   = (const float*)d_in[0];  // (256,16,1024) f32
  const float* pos = (const float*)d_in[1];
  const float* neg = (const float*)d_in[2];
  float* out = (float*)d_out;

  float* ws = (float*)d_ws;
  float* pm         = ws;                       // 4096*128 = 2 MB
  float* pl         = pm + (size_t)4096 * CS;   // 4096*128 = 2 MB
  float* blocks_raw = pl + (size_t)4096 * CS;   // 256*256
  unsigned char* ob = (unsigned char*)(blocks_raw + 65536);  // 3 x 4 MB fp8
  unsigned char* pb = ob + (size_t)ARR_ELEMS;
  unsigned char* nb = pb + (size_t)ARR_ELEMS;

  hipMemsetAsync(out, 0, sizeof(float), stream);
  cvt_kernel<<<3 * ARR_ELEMS / 8 / 256, 256, 0, stream>>>(o, pos, neg, ob, pb, nb);
  gemm_lse_kernel<<<RT * NCS, 256, 0, stream>>>(ob, pb, nb, pm, pl, blocks_raw);
  hungarian_kernel<<<256, 64, 0, stream>>>(blocks_raw, pm, pl, out);
}

// Round 11
// 222.392 us; speedup vs baseline: 2.1682x; 1.7406x over previous
//
#include <hip/hip_runtime.h>
#include <hip/hip_bf16.h>
#include <math.h>

#define Ddim 1024
#define Mrows 4096
#define Ncols 8192
#define BM 128
#define BN 128
#define BK 32
#define NCS 64                         // 64 col-split blocks of 128 cols
#define CS 128                         // lse partials per row (64 cols each)
#define RT (Mrows / BM)                // 32
#define KITERS (Ddim / BK)             // 32
#define SCALE 20.0f                    // 1/TEMPERATURE
#define ARR_ELEMS (Mrows * Ddim)       // 4194304 per input array

typedef __bf16 bf16_t;
typedef __bf16 bf16x8 __attribute__((ext_vector_type(8)));
typedef float f32x4 __attribute__((ext_vector_type(4)));

// global->LDS DMA, 16B per lane, lds dest = wave-uniform base + lane*16
#define LOAD16_TO_LDS(g, l)                                                  \
  __builtin_amdgcn_global_load_lds(                                          \
      (const __attribute__((address_space(1))) void*)(g),                    \
      (__attribute__((address_space(3))) void*)(l), 16, 0, 0)

// ---------------------------------------------------------------------------
// Kernel 0: f32 -> bf16 conversion pre-pass; block 0 also zeroes the output
// scalar (replaces the hipMemsetAsync dispatch; cvt precedes hungarian's
// atomicAdds in stream order).
// ---------------------------------------------------------------------------
__global__ __launch_bounds__(256) void cvt_kernel(
    const float* __restrict__ o, const float* __restrict__ pos,
    const float* __restrict__ neg, bf16_t* __restrict__ ob,
    bf16_t* __restrict__ pb, bf16_t* __restrict__ nb,
    float* __restrict__ out)
{
  if (blockIdx.x == 0 && threadIdx.x == 0) out[0] = 0.f;
  const int idx = blockIdx.x * 256 + threadIdx.x;   // 0 .. 3*ARR/8-1
  const int seg = idx >> 19;                        // ARR_ELEMS/8 = 2^19
  const int off = idx & ((1 << 19) - 1);
  const float* src = (seg == 0) ? o : (seg == 1) ? pos : neg;
  bf16_t* dst = (seg == 0) ? ob : (seg == 1) ? pb : nb;
  const float4 v0 = *(const float4*)(src + (size_t)off * 8);
  const float4 v1 = *(const float4*)(src + (size_t)off * 8 + 4);
  bf16x8 r = {(bf16_t)v0.x, (bf16_t)v0.y, (bf16_t)v0.z, (bf16_t)v0.w,
              (bf16_t)v1.x, (bf16_t)v1.y, (bf16_t)v1.z, (bf16_t)v1.w};
  *(bf16x8*)(dst + (size_t)off * 8) = r;
}

// ---------------------------------------------------------------------------
// Kernel 1: bf16 GEMM (o · emb^T) + partial LSE + diagonal-block extraction.
// R7 configuration (best measured: 94 us, MfmaUtil ~31%, 0 conflicts, 0
// spill): 128x128 block, 2x2 wave grid of 64x64 wave tiles, 16 MFMA per 8
// ds_read_b128, 64-AGPR accumulator, 4 waves/SIMD. Double-buffered LDS +
// global_load_lds DMA + XOR source-swizzle.
// R5 lesson: acc[][] indexed only with compile-time constants.
// R9/R10 lesson: the fp8 mfma_scale path scratch-spills and bank-conflicts
// under this structure — do not revisit without a standalone probe.
// ---------------------------------------------------------------------------
__global__ __launch_bounds__(256, 4) void gemm_lse_kernel(
    const bf16_t* __restrict__ ob, const bf16_t* __restrict__ pb,
    const bf16_t* __restrict__ nb, float* __restrict__ pm,
    float* __restrict__ pl, float* __restrict__ blocks_raw)
{
  __shared__ bf16_t As[2][BM * BK];   // 2 x 8 KB
  __shared__ bf16_t Bs[2][BN * BK];   // 2 x 8 KB

  const int bid = blockIdx.x;
  const int rt = bid >> 6;        // 0..31
  const int cs = bid & 63;        // 0..63
  const int row0 = rt * BM;
  const bf16_t* Eb = (cs < 32) ? (pb + (size_t)cs * BN * Ddim)
                               : (nb + (size_t)(cs - 32) * BN * Ddim);

  const int t = threadIdx.x;
  const int wave = t >> 6;
  const int wr = wave & 1;        // row half (64 rows)
  const int wc = wave >> 1;       // col half (64 cols)
  const int lane = t & 63;
  const int quad = lane >> 4;
  const int l16 = lane & 15;
  const int koff = ((quad ^ ((l16 >> 1) & 3)) << 3);   // fragment chunk offset
  const int lr4 = lane >> 2;                            // staging row-in-16
  const int cstg = lane & 3;                            // staging chunk id

  f32x4 acc[4][4];
#pragma unroll
  for (int a = 0; a < 4; ++a)
#pragma unroll
    for (int b = 0; b < 4; ++b) acc[a][b] = (f32x4){0.f, 0.f, 0.f, 0.f};

  // prologue: stage tile 0 into buffer 0 (each wave stages 32 rows of A & B)
#pragma unroll
  for (int cl = 0; cl < 2; ++cl) {
    const int r = wave * 32 + cl * 16 + lr4;
    const int gc = cstg ^ ((r >> 1) & 3);
    LOAD16_TO_LDS(ob + (size_t)(row0 + r) * Ddim + gc * 8,
                  &As[0][(wave * 32 + cl * 16) * BK]);
    LOAD16_TO_LDS(Eb + (size_t)r * Ddim + gc * 8,
                  &Bs[0][(wave * 32 + cl * 16) * BK]);
  }

  int p = 0;
  for (int kc = 0; kc < KITERS; ++kc) {
    __syncthreads();   // drains DMA for buf p; protects buf p^1 reuse
    if (kc + 1 < KITERS) {
      const int k0 = (kc + 1) * BK;
#pragma unroll
      for (int cl = 0; cl < 2; ++cl) {
        const int r = wave * 32 + cl * 16 + lr4;
        const int gc = cstg ^ ((r >> 1) & 3);
        LOAD16_TO_LDS(ob + (size_t)(row0 + r) * Ddim + k0 + gc * 8,
                      &As[p ^ 1][(wave * 32 + cl * 16) * BK]);
        LOAD16_TO_LDS(Eb + (size_t)r * Ddim + k0 + gc * 8,
                      &Bs[p ^ 1][(wave * 32 + cl * 16) * BK]);
      }
    }

    bf16x8 af[4];
#pragma unroll
    for (int fm = 0; fm < 4; ++fm)
      af[fm] = *(const bf16x8*)(&As[p][(wr * 64 + fm * 16 + l16) * BK + koff]);
#pragma unroll
    for (int fn = 0; fn < 4; ++fn) {
      const bf16x8 bf = *(const bf16x8*)(&Bs[p][(wc * 64 + fn * 16 + l16) * BK + koff]);
#pragma unroll
      for (int fm = 0; fm < 4; ++fm)
        acc[fm][fn] = __builtin_amdgcn_mfma_f32_16x16x32_bf16(af[fm], bf, acc[fm][fn], 0, 0, 0);
    }
    p ^= 1;
  }

  // epilogue A: per-row (m, l) over this wave's 64 cols.
  // C/D: col = wc*64 + fn*16 + l16, row = wr*64 + fm*16 + quad*4 + r
  const int csp = cs * 2 + wc;     // partial-lse column index (0..127)
#pragma unroll
  for (int fm = 0; fm < 4; ++fm) {
#pragma unroll
    for (int r = 0; r < 4; ++r) {
      float s[4];
#pragma unroll
      for (int fn = 0; fn < 4; ++fn) s[fn] = acc[fm][fn][r] * SCALE;
      float m = fmaxf(fmaxf(s[0], s[1]), fmaxf(s[2], s[3]));
#pragma unroll
      for (int off = 1; off <= 8; off <<= 1)
        m = fmaxf(m, __shfl_xor(m, off, 64));   // row max over l16 group
      float l = 0.f;
#pragma unroll
      for (int fn = 0; fn < 4; ++fn) l += __expf(s[fn] - m);
#pragma unroll
      for (int off = 1; off <= 8; off <<= 1)
        l += __shfl_xor(l, off, 64);
      if (l16 == 0) {
        const int rg = row0 + wr * 64 + fm * 16 + quad * 4 + r;
        pm[(size_t)rg * CS + csp] = m;
        pl[(size_t)rg * CS + csp] = l;
      }
    }
  }

  // epilogue B: diagonal 16x16 sub-blocks (all acc indices compile-time).
  if (cs == rt && wr == wc) {
#pragma unroll
    for (int fm = 0; fm < 4; ++fm) {
      const int b = rt * 8 + wr * 4 + fm;
#pragma unroll
      for (int r = 0; r < 4; ++r)
        blocks_raw[b * 256 + (quad * 4 + r) * 16 + l16] = acc[fm][fm][r] * SCALE;
    }
  }
}

// ---------------------------------------------------------------------------
// Kernel 2: fused lse-combine + lane-parallel JV LAP + atomic loss.
// (R7 v2 — best measured variant.) Single wave per block, no barriers;
// u[] in row-lane registers; C in LDS.
// ---------------------------------------------------------------------------
__global__ __launch_bounds__(64) void hungarian_kernel(
    const float* __restrict__ blocks_raw, const float* __restrict__ pm,
    const float* __restrict__ pl, float* __restrict__ out)
{
  const int b = blockIdx.x;
  const int L = threadIdx.x;
  __shared__ float C[16][16];
  __shared__ float lse_s[16];

  for (int e = L; e < 256; e += 64)
    C[e >> 4][e & 15] = blocks_raw[b * 256 + e];

  // combine 128 partial (m,l) per row -> lse_s. lane = r + 16*g handles
  // partial chunk [g*32, g*32+32) of row r, then merges across g.
  {
    const int r = L & 15, g = L >> 4;
    const size_t base = (size_t)(b * 16 + r) * CS + g * 32;
    float m = -INFINITY, l = 0.f;
#pragma unroll
    for (int k = 0; k < 32; ++k) {
      const float m2 = pm[base + k];
      const float l2 = pl[base + k];
      const float M = fmaxf(m, m2);
      l = l * __expf(m - M) + l2 * __expf(m2 - M);
      m = M;
    }
#pragma unroll
    for (int off = 16; off <= 32; off <<= 1) {
      const float m2 = __shfl_xor(m, off, 64);
      const float l2 = __shfl_xor(l, off, 64);
      const float M = fmaxf(m, m2);
      l = l * __expf(m - M) + l2 * __expf(m2 - M);
      m = M;
    }
    if (g == 0) lse_s[r] = m + logf(l);
  }

  const float INF = 3.0e38f;
  float vj = 0.f, u_reg = 0.f;
  int pj = 0;
  float minv = INF;
  int wayj = 0;
  bool usedj = false, on_tree = false;

  for (int i = 1; i <= 16; ++i) {
    if (L == 0) pj = i;
    minv = INF; wayj = 0; usedj = false; on_tree = false;
    int j0 = 0;
    while (true) {
      usedj = usedj || (L == j0);
      const int i0 = __shfl(pj, j0, 64);
      if (L == i0) on_tree = true;
      const float ui0 = __shfl(u_reg, i0, 64);
      if (L >= 1 && L <= 16 && !usedj) {
        const float cur = -C[i0 - 1][L - 1] - ui0 - vj;
        if (cur < minv) { minv = cur; wayj = j0; }
      }
      float cand = (L >= 1 && L <= 16 && !usedj) ? minv : INF;
      int idx = L;
#pragma unroll
      for (int off = 16; off > 0; off >>= 1) {
        const float ov = __shfl_xor(cand, off, 32);
        const int oi = __shfl_xor(idx, off, 32);
        if (ov < cand || (ov == cand && oi < idx)) { cand = ov; idx = oi; }
      }
      const float delta = cand;                  // valid in lanes 0..31
      const int j1 = __builtin_amdgcn_readfirstlane(idx);
      if (L >= 1 && L <= 16) {
        if (usedj) vj -= delta; else minv -= delta;
        if (on_tree) u_reg += delta;
      }
      j0 = j1;
      const int pj0 = __shfl(pj, j0, 64);
      if (pj0 == 0) break;
    }
    while (j0 != 0) {
      const int j1a = __shfl(wayj, j0, 64);
      const int pjn = __shfl(pj, j1a, 64);
      if (L == j0) pj = pjn;
      j0 = j1a;
    }
  }

  float loss = 0.f;
  if (L >= 1 && L <= 16) loss = lse_s[pj - 1] - C[pj - 1][L - 1];
#pragma unroll
  for (int off = 32; off > 0; off >>= 1) loss += __shfl_down(loss, off, 64);
  if (L == 0) atomicAdd(out, loss * (1.0f / 4096.0f));
}

extern "C" void kernel_launch(void* const* d_in, const int* in_sizes, int n_in,
                              void* d_out, int out_size, void* d_ws, size_t ws_size,
                              hipStream_t stream) {
  const float* o   = (const float*)d_in[0];  // (256,16,1024) f32
  const float* pos = (const float*)d_in[1];
  const float* neg = (const float*)d_in[2];
  float* out = (float*)d_out;

  float* ws = (float*)d_ws;
  float* pm         = ws;                       // 4096*128 = 2 MB
  float* pl         = pm + (size_t)4096 * CS;   // 4096*128 = 2 MB
  float* blocks_raw = pl + (size_t)4096 * CS;   // 256*256
  bf16_t* ob = (bf16_t*)(blocks_raw + 65536);   // 3 x 4194304 bf16
  bf16_t* pb = ob + (size_t)ARR_ELEMS;
  bf16_t* nb = pb + (size_t)ARR_ELEMS;

  cvt_kernel<<<3 * ARR_ELEMS / 8 / 256, 256, 0, stream>>>(o, pos, neg, ob, pb, nb, out);
  gemm_lse_kernel<<<RT * NCS, 256, 0, stream>>>(ob, pb, nb, pm, pl, blocks_raw);
  hungarian_kernel<<<256, 64, 0, stream>>>(blocks_raw, pm, pl, out);
}

// Round 12
// 221.806 us; speedup vs baseline: 2.1740x; 1.0026x over previous
//
#include <hip/hip_runtime.h>
#include <hip/hip_bf16.h>
#include <math.h>

#define Ddim 1024
#define Mrows 4096
#define Ncols 8192
#define BM 128
#define BN 128
#define BK 32
#define NCS 64                         // 64 col-split blocks of 128 cols
#define CS 64                          // lse partials per row (128 cols each)
#define RT (Mrows / BM)                // 32
#define KITERS (Ddim / BK)             // 32
#define SCALE 20.0f                    // 1/TEMPERATURE
#define ARR_ELEMS (Mrows * Ddim)       // 4194304 per input array

typedef __bf16 bf16_t;
typedef __bf16 bf16x8 __attribute__((ext_vector_type(8)));
typedef float f32x4 __attribute__((ext_vector_type(4)));

// global->LDS DMA, 16B per lane, lds dest = wave-uniform base + lane*16
#define LOAD16_TO_LDS(g, l)                                                  \
  __builtin_amdgcn_global_load_lds(                                          \
      (const __attribute__((address_space(1))) void*)(g),                    \
      (__attribute__((address_space(3))) void*)(l), 16, 0, 0)

// ---------------------------------------------------------------------------
// Kernel 0: f32 -> bf16 conversion pre-pass; thread (0,0) also zeroes the
// output scalar (stream order guarantees it lands before hungarian's atomics).
// ---------------------------------------------------------------------------
__global__ __launch_bounds__(256) void cvt_kernel(
    const float* __restrict__ o, const float* __restrict__ pos,
    const float* __restrict__ neg, bf16_t* __restrict__ ob,
    bf16_t* __restrict__ pb, bf16_t* __restrict__ nb,
    float* __restrict__ out)
{
  if (blockIdx.x == 0 && threadIdx.x == 0) out[0] = 0.f;
  const int idx = blockIdx.x * 256 + threadIdx.x;   // 0 .. 3*ARR/8-1
  const int seg = idx >> 19;                        // ARR_ELEMS/8 = 2^19
  const int off = idx & ((1 << 19) - 1);
  const float* src = (seg == 0) ? o : (seg == 1) ? pos : neg;
  bf16_t* dst = (seg == 0) ? ob : (seg == 1) ? pb : nb;
  const float4 v0 = *(const float4*)(src + (size_t)off * 8);
  const float4 v1 = *(const float4*)(src + (size_t)off * 8 + 4);
  bf16x8 r = {(bf16_t)v0.x, (bf16_t)v0.y, (bf16_t)v0.z, (bf16_t)v0.w,
              (bf16_t)v1.x, (bf16_t)v1.y, (bf16_t)v1.z, (bf16_t)v1.w};
  *(bf16x8*)(dst + (size_t)off * 8) = r;
}

// ---------------------------------------------------------------------------
// Kernel 1: bf16 GEMM (o · emb^T) + partial LSE + diagonal-block extraction.
// R4's stripe config (fastest measured gemm: 88 us): 128x128 block, 4 waves
// of 32x128 stripes (2 A-frags x 8 B-frags = 16 MFMA / 10 ds_read_b128),
// 64-AGPR acc, 4 waves/SIMD. Double-buffered LDS + global_load_lds DMA +
// XOR source-swizzle (0 conflicts, verified R4-R11).
// Diagonal extraction via R6's guarded constant-index unroll:
// fn == 2*wave+fm selects the diag sub-block; acc indices stay compile-time
// (R5 scratch-demotion lesson).
// ---------------------------------------------------------------------------
__global__ __launch_bounds__(256, 4) void gemm_lse_kernel(
    const bf16_t* __restrict__ ob, const bf16_t* __restrict__ pb,
    const bf16_t* __restrict__ nb, float* __restrict__ pm,
    float* __restrict__ pl, float* __restrict__ blocks_raw)
{
  __shared__ bf16_t As[2][BM * BK];   // 2 x 8 KB
  __shared__ bf16_t Bs[2][BN * BK];   // 2 x 8 KB

  const int bid = blockIdx.x;
  const int rt = bid >> 6;        // 0..31
  const int cs = bid & 63;        // 0..63
  const int row0 = rt * BM;
  const bf16_t* Eb = (cs < 32) ? (pb + (size_t)cs * BN * Ddim)
                               : (nb + (size_t)(cs - 32) * BN * Ddim);

  const int t = threadIdx.x;
  const int wave = t >> 6;
  const int lane = t & 63;
  const int quad = lane >> 4;
  const int l16 = lane & 15;
  const int koff = ((quad ^ ((l16 >> 1) & 3)) << 3);   // fragment chunk offset
  const int lr4 = lane >> 2;                            // staging row-in-16
  const int cstg = lane & 3;                            // staging chunk id

  f32x4 acc[2][8];
#pragma unroll
  for (int a = 0; a < 2; ++a)
#pragma unroll
    for (int b = 0; b < 8; ++b) acc[a][b] = (f32x4){0.f, 0.f, 0.f, 0.f};

  // prologue: stage tile 0 into buffer 0 (each wave stages 32 rows of A & B)
#pragma unroll
  for (int cl = 0; cl < 2; ++cl) {
    const int r = wave * 32 + cl * 16 + lr4;
    const int gc = cstg ^ ((r >> 1) & 3);
    LOAD16_TO_LDS(ob + (size_t)(row0 + r) * Ddim + gc * 8,
                  &As[0][(wave * 32 + cl * 16) * BK]);
    LOAD16_TO_LDS(Eb + (size_t)r * Ddim + gc * 8,
                  &Bs[0][(wave * 32 + cl * 16) * BK]);
  }

  int p = 0;
  for (int kc = 0; kc < KITERS; ++kc) {
    __syncthreads();   // drains DMA for buf p; protects buf p^1 reuse
    if (kc + 1 < KITERS) {
      const int k0 = (kc + 1) * BK;
#pragma unroll
      for (int cl = 0; cl < 2; ++cl) {
        const int r = wave * 32 + cl * 16 + lr4;
        const int gc = cstg ^ ((r >> 1) & 3);
        LOAD16_TO_LDS(ob + (size_t)(row0 + r) * Ddim + k0 + gc * 8,
                      &As[p ^ 1][(wave * 32 + cl * 16) * BK]);
        LOAD16_TO_LDS(Eb + (size_t)r * Ddim + k0 + gc * 8,
                      &Bs[p ^ 1][(wave * 32 + cl * 16) * BK]);
      }
    }

    const int rowA0 = wave * 32 + l16;
    const bf16x8 a0 = *(const bf16x8*)(&As[p][rowA0 * BK + koff]);
    const bf16x8 a1 = *(const bf16x8*)(&As[p][(rowA0 + 16) * BK + koff]);
#pragma unroll
    for (int fn = 0; fn < 8; ++fn) {
      const bf16x8 bf = *(const bf16x8*)(&Bs[p][(fn * 16 + l16) * BK + koff]);
      acc[0][fn] = __builtin_amdgcn_mfma_f32_16x16x32_bf16(a0, bf, acc[0][fn], 0, 0, 0);
      acc[1][fn] = __builtin_amdgcn_mfma_f32_16x16x32_bf16(a1, bf, acc[1][fn], 0, 0, 0);
    }
    p ^= 1;
  }

  // epilogue A: per-row (m, l) over this block's 128 cols.
  // C/D: col = fn*16 + l16, row = wave*32 + fm*16 + quad*4 + r
#pragma unroll
  for (int fm = 0; fm < 2; ++fm) {
#pragma unroll
    for (int r = 0; r < 4; ++r) {
      float s[8];
#pragma unroll
      for (int fn = 0; fn < 8; ++fn) s[fn] = acc[fm][fn][r] * SCALE;
      float m = s[0];
#pragma unroll
      for (int fn = 1; fn < 8; ++fn) m = fmaxf(m, s[fn]);
#pragma unroll
      for (int off = 1; off <= 8; off <<= 1)
        m = fmaxf(m, __shfl_xor(m, off, 64));   // row max over l16 group
      float l = 0.f;
#pragma unroll
      for (int fn = 0; fn < 8; ++fn) l += __expf(s[fn] - m);
#pragma unroll
      for (int off = 1; off <= 8; off <<= 1)
        l += __shfl_xor(l, off, 64);
      if (l16 == 0) {
        const int rg = row0 + wave * 32 + fm * 16 + quad * 4 + r;
        pm[(size_t)rg * CS + cs] = m;
        pl[(size_t)rg * CS + cs] = l;
      }
    }
  }

  // epilogue B: diagonal 16x16 sub-blocks (block cs == rt). Wave w, frag fm
  // holds diag sub-block d = 2*wave + fm at fn == d: guarded constant-index
  // unroll keeps every acc access compile-time.
  if (cs == rt) {
#pragma unroll
    for (int fm = 0; fm < 2; ++fm) {
      const int d = 2 * wave + fm;         // runtime, but acc idx below const
      const int b = rt * 8 + d;
#pragma unroll
      for (int fn = 0; fn < 8; ++fn) {
        if (fn == d) {
#pragma unroll
          for (int r = 0; r < 4; ++r)
            blocks_raw[b * 256 + (quad * 4 + r) * 16 + l16] = acc[fm][fn][r] * SCALE;
        }
      }
    }
  }
}

// ---------------------------------------------------------------------------
// Kernel 2: fused lse-combine + lane-parallel JV LAP + atomic loss.
// (R7 v2 solve — best measured; R4-proven CS=64 combine.)
// ---------------------------------------------------------------------------
__global__ __launch_bounds__(64) void hungarian_kernel(
    const float* __restrict__ blocks_raw, const float* __restrict__ pm,
    const float* __restrict__ pl, float* __restrict__ out)
{
  const int b = blockIdx.x;
  const int L = threadIdx.x;
  __shared__ float C[16][16];
  __shared__ float lse_s[16];

  for (int e = L; e < 256; e += 64)
    C[e >> 4][e & 15] = blocks_raw[b * 256 + e];

  // combine 64 partial (m,l) per row -> lse_s. lane = r + 16*g handles
  // partial chunk [g*16, g*16+16) of row r, then merges across g.
  {
    const int r = L & 15, g = L >> 4;
    const size_t base = (size_t)(b * 16 + r) * CS + g * 16;
    float m = -INFINITY, l = 0.f;
#pragma unroll
    for (int k = 0; k < 16; ++k) {
      const float m2 = pm[base + k];
      const float l2 = pl[base + k];
      const float M = fmaxf(m, m2);
      l = l * __expf(m - M) + l2 * __expf(m2 - M);
      m = M;
    }
#pragma unroll
    for (int off = 16; off <= 32; off <<= 1) {
      const float m2 = __shfl_xor(m, off, 64);
      const float l2 = __shfl_xor(l, off, 64);
      const float M = fmaxf(m, m2);
      l = l * __expf(m - M) + l2 * __expf(m2 - M);
      m = M;
    }
    if (g == 0) lse_s[r] = m + logf(l);
  }

  const float INF = 3.0e38f;
  float vj = 0.f, u_reg = 0.f;
  int pj = 0;
  float minv = INF;
  int wayj = 0;
  bool usedj = false, on_tree = false;

  for (int i = 1; i <= 16; ++i) {
    if (L == 0) pj = i;
    minv = INF; wayj = 0; usedj = false; on_tree = false;
    int j0 = 0;
    while (true) {
      usedj = usedj || (L == j0);
      const int i0 = __shfl(pj, j0, 64);
      if (L == i0) on_tree = true;
      const float ui0 = __shfl(u_reg, i0, 64);
      if (L >= 1 && L <= 16 && !usedj) {
        const float cur = -C[i0 - 1][L - 1] - ui0 - vj;
        if (cur < minv) { minv = cur; wayj = j0; }
      }
      float cand = (L >= 1 && L <= 16 && !usedj) ? minv : INF;
      int idx = L;
#pragma unroll
      for (int off = 16; off > 0; off >>= 1) {
        const float ov = __shfl_xor(cand, off, 32);
        const int oi = __shfl_xor(idx, off, 32);
        if (ov < cand || (ov == cand && oi < idx)) { cand = ov; idx = oi; }
      }
      const float delta = cand;                  // valid in lanes 0..31
      const int j1 = __builtin_amdgcn_readfirstlane(idx);
      if (L >= 1 && L <= 16) {
        if (usedj) vj -= delta; else minv -= delta;
        if (on_tree) u_reg += delta;
      }
      j0 = j1;
      const int pj0 = __shfl(pj, j0, 64);
      if (pj0 == 0) break;
    }
    while (j0 != 0) {
      const int j1a = __shfl(wayj, j0, 64);
      const int pjn = __shfl(pj, j1a, 64);
      if (L == j0) pj = pjn;
      j0 = j1a;
    }
  }

  float loss = 0.f;
  if (L >= 1 && L <= 16) loss = lse_s[pj - 1] - C[pj - 1][L - 1];
#pragma unroll
  for (int off = 32; off > 0; off >>= 1) loss += __shfl_down(loss, off, 64);
  if (L == 0) atomicAdd(out, loss * (1.0f / 4096.0f));
}

extern "C" void kernel_launch(void* const* d_in, const int* in_sizes, int n_in,
                              void* d_out, int out_size, void* d_ws, size_t ws_size,
                              hipStream_t stream) {
  const float* o   = (const float*)d_in[0];  // (256,16,1024) f32
  const float* pos = (const float*)d_in[1];
  const float* neg = (const float*)d_in[2];
  float* out = (float*)d_out;

  float* ws = (float*)d_ws;
  float* pm         = ws;                       // 4096*64 = 1 MB
  float* pl         = pm + (size_t)4096 * CS;   // 4096*64 = 1 MB
  float* blocks_raw = pl + (size_t)4096 * CS;   // 256*256
  bf16_t* ob = (bf16_t*)(blocks_raw + 65536);   // 3 x 4194304 bf16
  bf16_t* pb = ob + (size_t)ARR_ELEMS;
  bf16_t* nb = pb + (size_t)ARR_ELEMS;

  cvt_kernel<<<3 * ARR_ELEMS / 8 / 256, 256, 0, stream>>>(o, pos, neg, ob, pb, nb, out);
  gemm_lse_kernel<<<RT * NCS, 256, 0, stream>>>(ob, pb, nb, pm, pl, blocks_raw);
  hungarian_kernel<<<256, 64, 0, stream>>>(blocks_raw, pm, pl, out);
}